// Round 2
// baseline (187.850 us; speedup 1.0000x reference)
//
#include <hip/hip_runtime.h>
#include <hip/hip_bf16.h>
#include <hip/hip_fp16.h>
#include <math.h>

typedef _Float16 f16;
typedef _Float16 f16x8 __attribute__((ext_vector_type(8)));
typedef _Float16 f16x4 __attribute__((ext_vector_type(4)));
typedef _Float16 f16x2 __attribute__((ext_vector_type(2)));
typedef unsigned short u16x8v __attribute__((ext_vector_type(8)));
typedef float f32x4 __attribute__((ext_vector_type(4)));

namespace {
constexpr int B = 2;
constexpr int H = 16;
constexpr int S = 2048;
constexpr int D = 64;
constexpr int E = 1024;
constexpr int LP = 72;   // LDS row stride (f16) for attn tiles: rows 16B-aligned (144 B)
// fold 1/sqrt(64) * log2(e) into Q so softmax uses exp2 directly
constexpr float QSCALE = 0.125f * 1.4426950408889634f;
}

#define GLOBAL_LOAD_LDS16(gp, lp)                                              \
  __builtin_amdgcn_global_load_lds(                                            \
      (const __attribute__((address_space(1))) void*)(gp),                     \
      (__attribute__((address_space(3))) void*)(lp), 16, 0, 0)

// ---------- prep: [blocks 0..1023] Wd fp32->f16 ; [blocks 1024..1039] Wkv = Wk*Wv, bkv = Wk*bv + bk
__global__ __launch_bounds__(256) void prep(const float* __restrict__ Wd, f16* __restrict__ wd16,
                                            const float* __restrict__ Wk, const float* __restrict__ Wv,
                                            const float* __restrict__ bv, const float* __restrict__ bk,
                                            float* __restrict__ Wkv, float* __restrict__ bkv) {
  if (blockIdx.x < 1024) {
    const int i = blockIdx.x * 256 + threadIdx.x;
    const float4 f = ((const float4*)Wd)[i];
    f16x4 o;
    o.x = (f16)f.x; o.y = (f16)f.y; o.z = (f16)f.z; o.w = (f16)f.w;
    *(f16x4*)(wd16 + 4 * (size_t)i) = o;
  } else {
    const int g = (blockIdx.x - 1024) * 256 + threadIdx.x;   // 0..4095
    const int i = g >> 6, j = g & 63;
    float s = 0.f;
#pragma unroll 16
    for (int d = 0; d < 64; ++d) s = fmaf(Wk[i * 64 + d], Wv[d * 64 + j], s);
    Wkv[g] = s;
    if (g < 64) {
      float bb = bk[g];
#pragma unroll 16
      for (int d = 0; d < 64; ++d) bb = fmaf(Wk[g * 64 + d], bv[d], bb);
      bkv[g] = bb;
    }
  }
}

// ---------- all three per-head projections in ONE launch (blockIdx.y selects).
// x rows g = (b*S+s)*H + h (contiguous 64 f32); out[b][h][s][:] f16 = (x·W^T + bias)*scale
// SWAPPED MFMA operands: acc[nt][mt] = mfma(W-frag, x-frag) -> C[n][m]: lane holds
// row m = mt*16 + l15 (contiguous output row), n = nt*16 + quad*4 + r -> coalesced b64 stores.
__global__ __launch_bounds__(256) void proj3_mfma(const float* __restrict__ xq,
                                                  const float* __restrict__ xv,
                                                  const float* __restrict__ Wq,
                                                  const float* __restrict__ bq,
                                                  const float* __restrict__ Wv,
                                                  const float* __restrict__ bv,
                                                  const float* __restrict__ Wkv,
                                                  const float* __restrict__ bkv,
                                                  f16* __restrict__ qp,
                                                  f16* __restrict__ vp,
                                                  f16* __restrict__ kp) {
  const int which = blockIdx.y;
  const float* x    = (which == 0) ? xq : xv;
  const float* W    = (which == 0) ? Wq : (which == 1) ? Wv : Wkv;
  const float* bias = (which == 0) ? bq : (which == 1) ? bv : bkv;
  f16* out          = (which == 0) ? qp : (which == 1) ? vp : kp;
  const float scale = (which == 0) ? QSCALE : 1.0f;

  const int t = threadIdx.x, lane = t & 63, w = t >> 6;
  const int l15 = lane & 15, quad = lane >> 4;
  const int m0 = (blockIdx.x * 4 + w) * 64;

  f16x8 wf[4][2], af[4][2];
#pragma unroll
  for (int nt = 0; nt < 4; ++nt)
#pragma unroll
    for (int kc = 0; kc < 2; ++kc) {
      const float* g = W + (size_t)(nt * 16 + l15) * 64 + kc * 32 + quad * 8;
      const float4 a = *(const float4*)g, b2 = *(const float4*)(g + 4);
      f16x8 v;
      v[0]=(f16)a.x; v[1]=(f16)a.y; v[2]=(f16)a.z; v[3]=(f16)a.w;
      v[4]=(f16)b2.x; v[5]=(f16)b2.y; v[6]=(f16)b2.z; v[7]=(f16)b2.w;
      wf[nt][kc] = v;
    }
#pragma unroll
  for (int mt = 0; mt < 4; ++mt)
#pragma unroll
    for (int kc = 0; kc < 2; ++kc) {
      const float* g = x + (size_t)(m0 + mt * 16 + l15) * 64 + kc * 32 + quad * 8;
      const float4 a = *(const float4*)g, b2 = *(const float4*)(g + 4);
      f16x8 v;
      v[0]=(f16)a.x; v[1]=(f16)a.y; v[2]=(f16)a.z; v[3]=(f16)a.w;
      v[4]=(f16)b2.x; v[5]=(f16)b2.y; v[6]=(f16)b2.z; v[7]=(f16)b2.w;
      af[mt][kc] = v;
    }

  f32x4 acc[4][4];   // [nt (n-block)][mt (m-block)]
#pragma unroll
  for (int nt = 0; nt < 4; ++nt)
#pragma unroll
    for (int mt = 0; mt < 4; ++mt) acc[nt][mt] = (f32x4){0.f, 0.f, 0.f, 0.f};
#pragma unroll
  for (int kc = 0; kc < 2; ++kc)
#pragma unroll
    for (int nt = 0; nt < 4; ++nt)
#pragma unroll
      for (int mt = 0; mt < 4; ++mt)
        acc[nt][mt] = __builtin_amdgcn_mfma_f32_16x16x32_f16(wf[nt][kc], af[mt][kc], acc[nt][mt], 0, 0, 0);

  float4 bl4[4];
#pragma unroll
  for (int nt = 0; nt < 4; ++nt) bl4[nt] = *(const float4*)&bias[nt * 16 + quad * 4];

#pragma unroll
  for (int mt = 0; mt < 4; ++mt) {
    const int g = m0 + mt * 16 + l15;   // (b*S+s)*H + h
    const int h = g & 15, bs_ = g >> 4;
    const int b = bs_ >> 11, s = bs_ & 2047;
    f16* o = out + ((size_t)(b * H + h) * S + s) * 64 + quad * 4;
#pragma unroll
    for (int nt = 0; nt < 4; ++nt) {
      const float p0 = (acc[nt][mt][0] + bl4[nt].x) * scale;
      const float p1 = (acc[nt][mt][1] + bl4[nt].y) * scale;
      const float p2 = (acc[nt][mt][2] + bl4[nt].z) * scale;
      const float p3 = (acc[nt][mt][3] + bl4[nt].w) * scale;
      union { f16x4 v4; f16x2 hh[2]; } u;
      u.hh[0] = __builtin_bit_cast(f16x2, __builtin_amdgcn_cvt_pkrtz(p0, p1));
      u.hh[1] = __builtin_bit_cast(f16x2, __builtin_amdgcn_cvt_pkrtz(p2, p3));
      *(f16x4*)(o + nt * 16) = u.v4;
    }
  }
}

// ---------- MFMA flash attention (unchanged from round 1)
__global__ __launch_bounds__(256) void attn_mfma(const f16* __restrict__ qp,
                                                 const f16* __restrict__ kp,
                                                 const f16* __restrict__ vp,
                                                 f16* __restrict__ ao) {
  __shared__ f16 ks[2][64 * LP];       // K tile [kv][d], double-buffered
  __shared__ f16 vt[2][64 * LP];       // V^T tile [d][p], p = kv-permuted: kv(p) = (p&3)*16 + (p>>2)
  __shared__ f16 ps[4 * 32 * LP];      // per-wave P [32 q][p]
  const int t = threadIdx.x, lane = t & 63, w = t >> 6;
  const int l15 = lane & 15, quad = lane >> 4;
  const int bh = blockIdx.x;
  const int q0 = blockIdx.y * 128;
  const f16* qbase = qp + ((size_t)bh * S + q0 + w * 32) * D;
  const f16* kbase = kp + (size_t)bh * S * D;
  const f16* vbase = vp + (size_t)bh * S * D;
  f16* pw = ps + w * 32 * LP;

  const int kr = t >> 2, kc0 = (t & 3) * 16;          // K: row, col
  const int vd0 = (t >> 5) * 8, vpc0 = (t & 31) * 2;  // V: d block, phys col pair
  const int vkva = (vpc0 & 3) * 16 + (vpc0 >> 2);

  f16x8 qf[2][2];
#pragma unroll
  for (int mt = 0; mt < 2; ++mt)
#pragma unroll
    for (int kc = 0; kc < 2; ++kc)
      qf[mt][kc] = *(const f16x8*)(qbase + (size_t)(mt * 16 + l15) * D + kc * 32 + quad * 8);

  f16x8 vb4;
#pragma unroll
  for (int j = 0; j < 8; ++j) vb4[j] = (l15 == 0) ? (f16)1.0f : (f16)0.0f;

  f32x4 O[2][5];
#pragma unroll
  for (int mt = 0; mt < 2; ++mt)
#pragma unroll
    for (int nt = 0; nt < 5; ++nt) O[mt][nt] = (f32x4){0.f, 0.f, 0.f, 0.f};

  u16x8v ka, kb2, va, vb2;
  {
    const f16* gk = kbase + (size_t)kr * D + kc0;
    ka  = *(const u16x8v*)gk;
    kb2 = *(const u16x8v*)(gk + 8);
    const f16* gv = vbase + (size_t)vkva * D + vd0;
    va  = *(const u16x8v*)gv;
    vb2 = *(const u16x8v*)(gv + 16 * D);
  }
  {
    *(u16x8v*)&ks[0][kr * LP + kc0]     = ka;
    *(u16x8v*)&ks[0][kr * LP + kc0 + 8] = kb2;
#pragma unroll
    for (int j = 0; j < 8; ++j) {
      const unsigned pk = (unsigned)va[j] | ((unsigned)vb2[j] << 16);
      *(unsigned*)&vt[0][(vd0 + j) * LP + vpc0] = pk;
    }
  }

  int cur = 0;
  for (int kt = 0; kt < S / 64; ++kt) {
    if (kt + 1 < S / 64) {
      const f16* gk = kbase + ((size_t)(kt + 1) * 64 + kr) * D + kc0;
      ka  = *(const u16x8v*)gk;
      kb2 = *(const u16x8v*)(gk + 8);
      const f16* gv = vbase + ((size_t)(kt + 1) * 64 + vkva) * D + vd0;
      va  = *(const u16x8v*)gv;
      vb2 = *(const u16x8v*)(gv + 16 * D);
    }
    __asm__ volatile("s_waitcnt lgkmcnt(0)" ::: "memory");
    __builtin_amdgcn_s_barrier();
    __asm__ volatile("" ::: "memory");

    f32x4 sc[2][4];
#pragma unroll
    for (int mt = 0; mt < 2; ++mt)
#pragma unroll
      for (int nt = 0; nt < 4; ++nt) sc[mt][nt] = (f32x4){0.f, 0.f, 0.f, 0.f};
    __builtin_amdgcn_s_setprio(1);
#pragma unroll
    for (int kc = 0; kc < 2; ++kc)
#pragma unroll
      for (int nt = 0; nt < 4; ++nt) {
        const f16x8 bf = *(const f16x8*)&ks[cur][(nt * 16 + l15) * LP + kc * 32 + quad * 8];
#pragma unroll
        for (int mt = 0; mt < 2; ++mt)
          sc[mt][nt] = __builtin_amdgcn_mfma_f32_16x16x32_f16(qf[mt][kc], bf, sc[mt][nt], 0, 0, 0);
      }
    __builtin_amdgcn_s_setprio(0);

#pragma unroll
    for (int mt = 0; mt < 2; ++mt)
#pragma unroll
      for (int r = 0; r < 4; ++r) {
        const float p0 = __builtin_amdgcn_exp2f(sc[mt][0][r]);
        const float p1 = __builtin_amdgcn_exp2f(sc[mt][1][r]);
        const float p2 = __builtin_amdgcn_exp2f(sc[mt][2][r]);
        const float p3 = __builtin_amdgcn_exp2f(sc[mt][3][r]);
        union { f16x4 v4; f16x2 h[2]; } u;
        u.h[0] = __builtin_bit_cast(f16x2, __builtin_amdgcn_cvt_pkrtz(p0, p1));
        u.h[1] = __builtin_bit_cast(f16x2, __builtin_amdgcn_cvt_pkrtz(p2, p3));
        *(f16x4*)&pw[(mt * 16 + quad * 4 + r) * LP + l15 * 4] = u.v4;
      }
    __asm__ volatile("s_waitcnt lgkmcnt(0)" ::: "memory");

    f16x8 pa[2][2];
#pragma unroll
    for (int mt = 0; mt < 2; ++mt)
#pragma unroll
      for (int kc = 0; kc < 2; ++kc)
        pa[mt][kc] = *(const f16x8*)&pw[(mt * 16 + l15) * LP + kc * 32 + quad * 8];
    __builtin_amdgcn_s_setprio(1);
#pragma unroll
    for (int kc = 0; kc < 2; ++kc) {
#pragma unroll
      for (int nt = 0; nt < 4; ++nt) {
        const f16x8 vbf = *(const f16x8*)&vt[cur][(nt * 16 + l15) * LP + kc * 32 + quad * 8];
#pragma unroll
        for (int mt = 0; mt < 2; ++mt)
          O[mt][nt] = __builtin_amdgcn_mfma_f32_16x16x32_f16(pa[mt][kc], vbf, O[mt][nt], 0, 0, 0);
      }
#pragma unroll
      for (int mt = 0; mt < 2; ++mt)
        O[mt][4] = __builtin_amdgcn_mfma_f32_16x16x32_f16(pa[mt][kc], vb4, O[mt][4], 0, 0, 0);
    }
    __builtin_amdgcn_s_setprio(0);

    if (kt + 1 < S / 64) {
      const int nb = cur ^ 1;
      *(u16x8v*)&ks[nb][kr * LP + kc0]     = ka;
      *(u16x8v*)&ks[nb][kr * LP + kc0 + 8] = kb2;
#pragma unroll
      for (int j = 0; j < 8; ++j) {
        const unsigned pk = (unsigned)va[j] | ((unsigned)vb2[j] << 16);
        *(unsigned*)&vt[nb][(vd0 + j) * LP + vpc0] = pk;
      }
    }
    cur ^= 1;
  }

  const int b = bh >> 4, h = bh & 15;
#pragma unroll
  for (int mt = 0; mt < 2; ++mt)
#pragma unroll
    for (int r = 0; r < 4; ++r) {
      const float l = __shfl(O[mt][4][r], quad << 4, 64);
      const float inv = 1.f / l;
      const int row = q0 + w * 32 + mt * 16 + quad * 4 + r;
      f16* o = ao + ((size_t)b * S + row) * E + h * D;
#pragma unroll
      for (int nt = 0; nt < 4; ++nt)
        o[nt * 16 + l15] = (f16)(O[mt][nt][r] * inv);
    }
}

// ---------- dense: out[m][n] = sum_e A[m][e] * Wd16[n][e] + bd[n]
// m97-style: 128x128 tile, BK=64, global_load_lds width-16 staging into LDS double
// buffer issued BEFORE compute; one __syncthreads (vmcnt(0)+barrier) per K-step.
__global__ __launch_bounds__(256) void dense_mfma(const f16* __restrict__ A,
                                                  const f16* __restrict__ Wd16,
                                                  const float* __restrict__ bd,
                                                  float* __restrict__ out) {
  __shared__ f16 as[2][128 * 64];   // linear, no pad (gload_lds writes base + lane*16B)
  __shared__ f16 bs[2][128 * 64];
  const int t = threadIdx.x;
  const int lane = t & 63;
  const int w = t >> 6;
  const int l15 = lane & 15;
  const int quad = lane >> 4;
  const int m0 = blockIdx.x * 128;
  const int n0 = blockIdx.y * 128;
  const int wm = (w >> 1) * 64, wn = (w & 1) * 64;

  // staging geometry: wave w covers rows [w*32, w*32+32), 4 calls x 8 rows each.
  // lane l: row = r0 + (l>>3), col chunk = (l&7)*8 f16 (16 B).
  const int srow = (lane >> 3);           // 0..7
  const int scol = (lane & 7) * 8;        // 0..56
  const f16* ga0 = A    + (size_t)(m0 + w * 32 + srow) * E + scol;
  const f16* gb0 = Wd16 + (size_t)(n0 + w * 32 + srow) * E + scol;

  constexpr int NT = E / 64;

  f32x4 acc[4][4];
#pragma unroll
  for (int mt = 0; mt < 4; ++mt)
#pragma unroll
    for (int nt = 0; nt < 4; ++nt) acc[mt][nt] = (f32x4){0.f, 0.f, 0.f, 0.f};

  // prologue: stage tile 0 into buf 0
#pragma unroll
  for (int i = 0; i < 4; ++i) {
    GLOBAL_LOAD_LDS16(ga0 + (size_t)(i * 8) * E, &as[0][(w * 32 + i * 8) * 64]);
    GLOBAL_LOAD_LDS16(gb0 + (size_t)(i * 8) * E, &bs[0][(w * 32 + i * 8) * 64]);
  }
  __syncthreads();   // vmcnt(0) drain + barrier -> buf0 ready

  int cur = 0;
  for (int kt = 0; kt < NT; ++kt) {
    // async stage of next tile into the other buffer (overlaps with compute below)
    if (kt + 1 < NT) {
      const int nb = cur ^ 1;
#pragma unroll
      for (int i = 0; i < 4; ++i) {
        GLOBAL_LOAD_LDS16(ga0 + (size_t)(i * 8) * E + (kt + 1) * 64, &as[nb][(w * 32 + i * 8) * 64]);
        GLOBAL_LOAD_LDS16(gb0 + (size_t)(i * 8) * E + (kt + 1) * 64, &bs[nb][(w * 32 + i * 8) * 64]);
      }
    }
    // compute current tile
    f16x8 af[4][2];
#pragma unroll
    for (int mt = 0; mt < 4; ++mt)
#pragma unroll
      for (int kc = 0; kc < 2; ++kc)
        af[mt][kc] = *(const f16x8*)&as[cur][(wm + mt * 16 + l15) * 64 + kc * 32 + quad * 8];
#pragma unroll
    for (int kc = 0; kc < 2; ++kc)
#pragma unroll
      for (int nt = 0; nt < 4; ++nt) {
        const f16x8 bf = *(const f16x8*)&bs[cur][(wn + nt * 16 + l15) * 64 + kc * 32 + quad * 8];
#pragma unroll
        for (int mt = 0; mt < 4; ++mt)
          acc[mt][nt] = __builtin_amdgcn_mfma_f32_16x16x32_f16(af[mt][kc], bf, acc[mt][nt], 0, 0, 0);
      }
    __syncthreads();   // vmcnt(0): next tile landed; barrier: all waves done reading cur
    cur ^= 1;
  }

#pragma unroll
  for (int nt = 0; nt < 4; ++nt) {
    const int col = n0 + wn + nt * 16 + l15;
    const float bdv = bd[col];
#pragma unroll
    for (int mt = 0; mt < 4; ++mt)
#pragma unroll
      for (int r = 0; r < 4; ++r)
        out[(size_t)(m0 + wm + mt * 16 + quad * 4 + r) * E + col] = acc[mt][nt][r] + bdv;
  }
}

extern "C" void kernel_launch(void* const* d_in, const int* in_sizes, int n_in,
                              void* d_out, int out_size, void* d_ws, size_t ws_size,
                              hipStream_t stream) {
  const float* queries = (const float*)d_in[0];
  const float* values  = (const float*)d_in[1];
  const float* Wv = (const float*)d_in[3];
  const float* bv = (const float*)d_in[4];
  const float* Wk = (const float*)d_in[5];
  const float* bk = (const float*)d_in[6];
  const float* Wq = (const float*)d_in[7];
  const float* bq = (const float*)d_in[8];
  const float* Wd = (const float*)d_in[9];
  const float* bd = (const float*)d_in[10];
  float* out = (float*)d_out;

  char* ws = (char*)d_ws;
  f16* qp    = (f16*)(ws);                          // 8 MB [B,H,S,D]
  f16* kp    = (f16*)(ws + 8u * 1024 * 1024);       // 8 MB
  f16* vp    = (f16*)(ws + 16u * 1024 * 1024);      // 8 MB
  f16* ao    = (f16*)(ws + 24u * 1024 * 1024);      // 8 MB [B,S,E]
  f16* wd16  = (f16*)(ws + 32u * 1024 * 1024);      // 2 MB
  float* wkv = (float*)(ws + 34u * 1024 * 1024);    // 16 KB
  float* bkv = (float*)(ws + 34u * 1024 * 1024 + 16384);
  (void)ws_size; (void)in_sizes; (void)n_in; (void)out_size;

  prep<<<1040, 256, 0, stream>>>(Wd, wd16, Wk, Wv, bv, bk, wkv, bkv);
  proj3_mfma<<<dim3(256, 3), 256, 0, stream>>>(queries, values, Wq, bq, Wv, bv, wkv, bkv, qp, vp, kp);
  attn_mfma<<<dim3(B * H, S / 128), 256, 0, stream>>>(qp, kp, vp, ao);
  dense_mfma<<<dim3(B * S / 128, E / 128), 256, 0, stream>>>(ao, wd16, bd, out);
}

// Round 3
// 186.088 us; speedup vs baseline: 1.0095x; 1.0095x over previous
//
#include <hip/hip_runtime.h>
#include <hip/hip_bf16.h>
#include <hip/hip_fp16.h>
#include <math.h>

typedef _Float16 f16;
typedef _Float16 f16x8 __attribute__((ext_vector_type(8)));
typedef _Float16 f16x4 __attribute__((ext_vector_type(4)));
typedef _Float16 f16x2 __attribute__((ext_vector_type(2)));
typedef unsigned short u16x8v __attribute__((ext_vector_type(8)));
typedef float f32x4 __attribute__((ext_vector_type(4)));

namespace {
constexpr int B = 2;
constexpr int H = 16;
constexpr int S = 2048;
constexpr int D = 64;
constexpr int E = 1024;
// fold 1/sqrt(64) * log2(e) into Q so softmax uses exp2 directly
constexpr float QSCALE = 0.125f * 1.4426950408889634f;
}

#define GLOBAL_LOAD_LDS16(gp, lp)                                              \
  __builtin_amdgcn_global_load_lds(                                            \
      (const __attribute__((address_space(1))) void*)(gp),                     \
      (__attribute__((address_space(3))) void*)(lp), 16, 0, 0)

// ---------- prep: [blocks 0..1023] Wd fp32->f16 ; [blocks 1024..1039] Wkv = Wk*Wv, bkv = Wk*bv + bk
__global__ __launch_bounds__(256) void prep(const float* __restrict__ Wd, f16* __restrict__ wd16,
                                            const float* __restrict__ Wk, const float* __restrict__ Wv,
                                            const float* __restrict__ bv, const float* __restrict__ bk,
                                            float* __restrict__ Wkv, float* __restrict__ bkv) {
  if (blockIdx.x < 1024) {
    const int i = blockIdx.x * 256 + threadIdx.x;
    const float4 f = ((const float4*)Wd)[i];
    f16x4 o;
    o.x = (f16)f.x; o.y = (f16)f.y; o.z = (f16)f.z; o.w = (f16)f.w;
    *(f16x4*)(wd16 + 4 * (size_t)i) = o;
  } else {
    const int g = (blockIdx.x - 1024) * 256 + threadIdx.x;   // 0..4095
    const int i = g >> 6, j = g & 63;
    float s = 0.f;
#pragma unroll 16
    for (int d = 0; d < 64; ++d) s = fmaf(Wk[i * 64 + d], Wv[d * 64 + j], s);
    Wkv[g] = s;
    if (g < 64) {
      float bb = bk[g];
#pragma unroll 16
      for (int d = 0; d < 64; ++d) bb = fmaf(Wk[g * 64 + d], bv[d], bb);
      bkv[g] = bb;
    }
  }
}

// ---------- projections: blockIdx.y==0 -> Q; ==1 -> V then K (x loaded once, two weight passes).
// x rows g = (b*S+s)*H + h (contiguous 64 f32); out[b][h][s][:] f16 = (x·W^T + bias)*scale
// SWAPPED operands: acc[nt][mt] = mfma(W-frag, x-frag) -> lane holds row m = mt*16+l15,
// cols n = nt*16 + quad*4 + r -> coalesced b64 stores.
__global__ __launch_bounds__(256) void proj3_mfma(const float* __restrict__ xq,
                                                  const float* __restrict__ xv,
                                                  const float* __restrict__ Wq,
                                                  const float* __restrict__ bq,
                                                  const float* __restrict__ Wv,
                                                  const float* __restrict__ bv,
                                                  const float* __restrict__ Wkv,
                                                  const float* __restrict__ bkv,
                                                  f16* __restrict__ qp,
                                                  f16* __restrict__ vp,
                                                  f16* __restrict__ kp) {
  const int which = blockIdx.y;
  const float* x = which ? xv : xq;

  const int t = threadIdx.x, lane = t & 63, w = t >> 6;
  const int l15 = lane & 15, quad = lane >> 4;
  const int m0 = (blockIdx.x * 4 + w) * 64;

  f16x8 af[4][2];
#pragma unroll
  for (int mt = 0; mt < 4; ++mt)
#pragma unroll
    for (int kc = 0; kc < 2; ++kc) {
      const float* g = x + (size_t)(m0 + mt * 16 + l15) * 64 + kc * 32 + quad * 8;
      const float4 a = *(const float4*)g, b2 = *(const float4*)(g + 4);
      f16x8 v;
      v[0]=(f16)a.x; v[1]=(f16)a.y; v[2]=(f16)a.z; v[3]=(f16)a.w;
      v[4]=(f16)b2.x; v[5]=(f16)b2.y; v[6]=(f16)b2.z; v[7]=(f16)b2.w;
      af[mt][kc] = v;
    }

  const int npass = which ? 2 : 1;
  for (int pass = 0; pass < npass; ++pass) {
    const float* W    = which ? (pass ? Wkv : Wv) : Wq;
    const float* bias = which ? (pass ? bkv : bv) : bq;
    f16* out          = which ? (pass ? kp : vp) : qp;
    const float scale = which ? 1.0f : QSCALE;

    f16x8 wf[4][2];
#pragma unroll
    for (int nt = 0; nt < 4; ++nt)
#pragma unroll
      for (int kc = 0; kc < 2; ++kc) {
        const float* g = W + (size_t)(nt * 16 + l15) * 64 + kc * 32 + quad * 8;
        const float4 a = *(const float4*)g, b2 = *(const float4*)(g + 4);
        f16x8 v;
        v[0]=(f16)a.x; v[1]=(f16)a.y; v[2]=(f16)a.z; v[3]=(f16)a.w;
        v[4]=(f16)b2.x; v[5]=(f16)b2.y; v[6]=(f16)b2.z; v[7]=(f16)b2.w;
        wf[nt][kc] = v;
      }

    f32x4 acc[4][4];   // [nt][mt]
#pragma unroll
    for (int nt = 0; nt < 4; ++nt)
#pragma unroll
      for (int mt = 0; mt < 4; ++mt) acc[nt][mt] = (f32x4){0.f, 0.f, 0.f, 0.f};
#pragma unroll
    for (int kc = 0; kc < 2; ++kc)
#pragma unroll
      for (int nt = 0; nt < 4; ++nt)
#pragma unroll
        for (int mt = 0; mt < 4; ++mt)
          acc[nt][mt] = __builtin_amdgcn_mfma_f32_16x16x32_f16(wf[nt][kc], af[mt][kc], acc[nt][mt], 0, 0, 0);

    float4 bl4[4];
#pragma unroll
    for (int nt = 0; nt < 4; ++nt) bl4[nt] = *(const float4*)&bias[nt * 16 + quad * 4];

#pragma unroll
    for (int mt = 0; mt < 4; ++mt) {
      const int g = m0 + mt * 16 + l15;   // (b*S+s)*H + h
      const int h = g & 15, bs_ = g >> 4;
      const int b = bs_ >> 11, s = bs_ & 2047;
      f16* o = out + ((size_t)(b * H + h) * S + s) * 64 + quad * 4;
#pragma unroll
      for (int nt = 0; nt < 4; ++nt) {
        const float p0 = (acc[nt][mt][0] + bl4[nt].x) * scale;
        const float p1 = (acc[nt][mt][1] + bl4[nt].y) * scale;
        const float p2 = (acc[nt][mt][2] + bl4[nt].z) * scale;
        const float p3 = (acc[nt][mt][3] + bl4[nt].w) * scale;
        union { f16x4 v4; f16x2 hh[2]; } u;
        u.hh[0] = __builtin_bit_cast(f16x2, __builtin_amdgcn_cvt_pkrtz(p0, p1));
        u.hh[1] = __builtin_bit_cast(f16x2, __builtin_amdgcn_cvt_pkrtz(p2, p3));
        *(f16x4*)(o + nt * 16) = u.v4;
      }
    }
  }
}

// ---------- MFMA flash attention v3: in-register P (swapped QK^T + chosen V permutation),
// XOR-swizzled unpadded K/V tiles, double-buffered, one raw barrier per tile.
// Perm: phys col p holds V row kv(p) = (p>>5)*32 + ((p&7)>>2)*16 + ((p>>3)&3)*4 + (p&3).
// Then PV A-frag elem j (phys k = kc*32+quad*8+j) = P[q=l15][kv] = exp2(sc[2kc+(j>>2)][mt][j&3]).
__global__ __launch_bounds__(256) void attn_mfma(const f16* __restrict__ qp,
                                                 const f16* __restrict__ kp,
                                                 const f16* __restrict__ vp,
                                                 f16* __restrict__ ao) {
  __shared__ f16 ks[2][64 * 64];   // K tile [kv][d], 16B-chunk XOR swizzle: c ^= row&7
  __shared__ f16 vt[2][64 * 64];   // V^T tile [d][p], same swizzle on p-chunks
  const int t = threadIdx.x, lane = t & 63, w = t >> 6;
  const int l15 = lane & 15, quad = lane >> 4;
  const int bh = blockIdx.x;
  const int q0 = blockIdx.y * 128;
  const f16* qbase = qp + ((size_t)bh * S + q0 + w * 32) * D;
  const f16* kbase = kp + (size_t)bh * S * D;
  const f16* vbase = vp + (size_t)bh * S * D;

  // staging geometry
  const int kr = t >> 2, kc2 = (t & 3) * 2;            // K: row, chunk pair (16B chunks)
  const int vd0 = (t >> 5) * 8;                         // V: d block (8 rows of vt)
  const int p0 = (t & 31) * 2;                          // V: phys col pair
  const int vkv = ((p0 >> 5) << 5) | (((p0 & 7) >> 2) << 4) | (((p0 >> 3) & 3) << 2) | (p0 & 3);
  const int vchunk = p0 >> 3, vsub = p0 & 7;            // chunk + within-chunk f16 offset

  f16x8 qf[2][2];
#pragma unroll
  for (int mt = 0; mt < 2; ++mt)
#pragma unroll
    for (int kc = 0; kc < 2; ++kc)
      qf[mt][kc] = *(const f16x8*)(qbase + (size_t)(mt * 16 + l15) * D + kc * 32 + quad * 8);

  // ones-column B-frag: B[k][n]=1 for n==0 -> row-sum (l) accumulates in O[mt][4] col 0
  f16x8 vb4;
#pragma unroll
  for (int j = 0; j < 8; ++j) vb4[j] = (l15 == 0) ? (f16)1.0f : (f16)0.0f;

  f32x4 O[2][5];
#pragma unroll
  for (int mt = 0; mt < 2; ++mt)
#pragma unroll
    for (int nt = 0; nt < 5; ++nt) O[mt][nt] = (f32x4){0.f, 0.f, 0.f, 0.f};

  u16x8v ka, kb2, va, vb2;
  {  // prologue: tile 0 glob->reg->LDS buf 0
    const f16* gk = kbase + (size_t)kr * D + kc2 * 8;
    ka  = *(const u16x8v*)gk;
    kb2 = *(const u16x8v*)(gk + 8);
    const f16* gv = vbase + (size_t)vkv * D + vd0;
    va  = *(const u16x8v*)gv;
    vb2 = *(const u16x8v*)(gv + D);
  }
  {
    *(u16x8v*)&ks[0][kr * 64 + ((kc2 ^ (kr & 7)) * 8)]       = ka;
    *(u16x8v*)&ks[0][kr * 64 + (((kc2 + 1) ^ (kr & 7)) * 8)] = kb2;
#pragma unroll
    for (int j = 0; j < 8; ++j) {
      const int d = vd0 + j;
      const unsigned pk = (unsigned)va[j] | ((unsigned)vb2[j] << 16);
      *(unsigned*)&vt[0][d * 64 + ((vchunk ^ (d & 7)) * 8) + vsub] = pk;
    }
  }

  int cur = 0;
  for (int kt = 0; kt < S / 64; ++kt) {
    // (A) issue next tile's global loads (latency hides under compute)
    if (kt + 1 < S / 64) {
      const f16* gk = kbase + ((size_t)(kt + 1) * 64 + kr) * D + kc2 * 8;
      ka  = *(const u16x8v*)gk;
      kb2 = *(const u16x8v*)(gk + 8);
      const f16* gv = vbase + ((size_t)(kt + 1) * 64 + vkv) * D + vd0;
      va  = *(const u16x8v*)gv;
      vb2 = *(const u16x8v*)(gv + D);
    }
    // (B) raw barrier: my ds_writes drained; vmcnt deliberately NOT drained
    __asm__ volatile("s_waitcnt lgkmcnt(0)" ::: "memory");
    __builtin_amdgcn_s_barrier();
    __asm__ volatile("" ::: "memory");

    // (C) QK^T swapped: sc[nt][mt] = mfma(K-frag, Q-frag) -> C[kv][q], q = l15 lane-local
    f32x4 sc[4][2];
#pragma unroll
    for (int nt = 0; nt < 4; ++nt)
#pragma unroll
      for (int mt = 0; mt < 2; ++mt) sc[nt][mt] = (f32x4){0.f, 0.f, 0.f, 0.f};
    __builtin_amdgcn_s_setprio(1);
#pragma unroll
    for (int kc = 0; kc < 2; ++kc)
#pragma unroll
      for (int nt = 0; nt < 4; ++nt) {
        const f16x8 kf = *(const f16x8*)&ks[cur][(nt * 16 + l15) * 64 + (((kc * 4 + quad) ^ (l15 & 7)) * 8)];
#pragma unroll
        for (int mt = 0; mt < 2; ++mt)
          sc[nt][mt] = __builtin_amdgcn_mfma_f32_16x16x32_f16(kf, qf[mt][kc], sc[nt][mt], 0, 0, 0);
      }
    __builtin_amdgcn_s_setprio(0);

    // P = exp2(sc), packed straight into PV A-frags (in-register, no LDS)
    f16x8 pa[2][2];
#pragma unroll
    for (int mt = 0; mt < 2; ++mt)
#pragma unroll
      for (int kc = 0; kc < 2; ++kc) {
        const f32x4 s0 = sc[2 * kc][mt], s1 = sc[2 * kc + 1][mt];
        union { f16x8 v8; f16x2 h[4]; } u;
        u.h[0] = __builtin_bit_cast(f16x2, __builtin_amdgcn_cvt_pkrtz(
            __builtin_amdgcn_exp2f(s0[0]), __builtin_amdgcn_exp2f(s0[1])));
        u.h[1] = __builtin_bit_cast(f16x2, __builtin_amdgcn_cvt_pkrtz(
            __builtin_amdgcn_exp2f(s0[2]), __builtin_amdgcn_exp2f(s0[3])));
        u.h[2] = __builtin_bit_cast(f16x2, __builtin_amdgcn_cvt_pkrtz(
            __builtin_amdgcn_exp2f(s1[0]), __builtin_amdgcn_exp2f(s1[1])));
        u.h[3] = __builtin_bit_cast(f16x2, __builtin_amdgcn_cvt_pkrtz(
            __builtin_amdgcn_exp2f(s1[2]), __builtin_amdgcn_exp2f(s1[3])));
        pa[mt][kc] = u.v8;
      }

    // PV += P * V (phys-k order matches vt perm); l accumulates in O[mt][4] col 0
    __builtin_amdgcn_s_setprio(1);
#pragma unroll
    for (int kc = 0; kc < 2; ++kc) {
#pragma unroll
      for (int nt = 0; nt < 4; ++nt) {
        const f16x8 vbf = *(const f16x8*)&vt[cur][(nt * 16 + l15) * 64 + (((kc * 4 + quad) ^ (l15 & 7)) * 8)];
#pragma unroll
        for (int mt = 0; mt < 2; ++mt)
          O[mt][nt] = __builtin_amdgcn_mfma_f32_16x16x32_f16(pa[mt][kc], vbf, O[mt][nt], 0, 0, 0);
      }
#pragma unroll
      for (int mt = 0; mt < 2; ++mt)
        O[mt][4] = __builtin_amdgcn_mfma_f32_16x16x32_f16(pa[mt][kc], vb4, O[mt][4], 0, 0, 0);
    }
    __builtin_amdgcn_s_setprio(0);

    // (D) write prefetched tile kt+1 into buf[cur^1]
    if (kt + 1 < S / 64) {
      const int nb = cur ^ 1;
      *(u16x8v*)&ks[nb][kr * 64 + ((kc2 ^ (kr & 7)) * 8)]       = ka;
      *(u16x8v*)&ks[nb][kr * 64 + (((kc2 + 1) ^ (kr & 7)) * 8)] = kb2;
#pragma unroll
      for (int j = 0; j < 8; ++j) {
        const int d = vd0 + j;
        const unsigned pk = (unsigned)va[j] | ((unsigned)vb2[j] << 16);
        *(unsigned*)&vt[nb][d * 64 + ((vchunk ^ (d & 7)) * 8) + vsub] = pk;
      }
    }
    cur ^= 1;
  }

  // epilogue: l lives in lane group's l15==0 lane of O[mt][4]
  const int b = bh >> 4, h = bh & 15;
#pragma unroll
  for (int mt = 0; mt < 2; ++mt)
#pragma unroll
    for (int r = 0; r < 4; ++r) {
      const float l = __shfl(O[mt][4][r], quad << 4, 64);
      const float inv = 1.f / l;
      const int row = q0 + w * 32 + mt * 16 + quad * 4 + r;
      f16* o = ao + ((size_t)b * S + row) * E + h * D;
#pragma unroll
      for (int nt = 0; nt < 4; ++nt)
        o[nt * 16 + l15] = (f16)(O[mt][nt][r] * inv);
    }
}

// ---------- dense: out[m][n] = sum_e A[m][e] * Wd16[n][e] + bd[n]
// 128x128 tile, BK=64, global_load_lds width-16 with PRE-SWIZZLED global source
// (linear LDS dest, rule #21) + XOR-swizzled reads -> conflict-free ds_read_b128.
__global__ __launch_bounds__(256) void dense_mfma(const f16* __restrict__ A,
                                                  const f16* __restrict__ Wd16,
                                                  const float* __restrict__ bd,
                                                  float* __restrict__ out) {
  __shared__ f16 as[2][128 * 64];
  __shared__ f16 bs[2][128 * 64];
  const int t = threadIdx.x;
  const int lane = t & 63;
  const int w = t >> 6;
  const int l15 = lane & 15;
  const int quad = lane >> 4;
  const int m0 = blockIdx.x * 128;
  const int n0 = blockIdx.y * 128;
  const int wm = (w >> 1) * 64, wn = (w & 1) * 64;

  // staging: lane l lands at LDS row base+(l>>3), chunk l&7 (linear). Pre-swizzle the
  // GLOBAL chunk: (l&7) ^ (l>>3) so LDS[r][c] holds global chunk c ^ (r&7).
  const int srow = (lane >> 3);
  const int schunk = (lane & 7) ^ srow;
  const f16* ga0 = A    + (size_t)(m0 + w * 32 + srow) * E + schunk * 8;
  const f16* gb0 = Wd16 + (size_t)(n0 + w * 32 + srow) * E + schunk * 8;

  constexpr int NT = E / 64;

  f32x4 acc[4][4];
#pragma unroll
  for (int mt = 0; mt < 4; ++mt)
#pragma unroll
    for (int nt = 0; nt < 4; ++nt) acc[mt][nt] = (f32x4){0.f, 0.f, 0.f, 0.f};

#pragma unroll
  for (int i = 0; i < 4; ++i) {
    GLOBAL_LOAD_LDS16(ga0 + (size_t)(i * 8) * E, &as[0][(w * 32 + i * 8) * 64]);
    GLOBAL_LOAD_LDS16(gb0 + (size_t)(i * 8) * E, &bs[0][(w * 32 + i * 8) * 64]);
  }
  __syncthreads();

  int cur = 0;
  for (int kt = 0; kt < NT; ++kt) {
    if (kt + 1 < NT) {
      const int nb = cur ^ 1;
#pragma unroll
      for (int i = 0; i < 4; ++i) {
        GLOBAL_LOAD_LDS16(ga0 + (size_t)(i * 8) * E + (kt + 1) * 64, &as[nb][(w * 32 + i * 8) * 64]);
        GLOBAL_LOAD_LDS16(gb0 + (size_t)(i * 8) * E + (kt + 1) * 64, &bs[nb][(w * 32 + i * 8) * 64]);
      }
    }
    f16x8 af[4][2];
#pragma unroll
    for (int mt = 0; mt < 4; ++mt)
#pragma unroll
      for (int kc = 0; kc < 2; ++kc)
        af[mt][kc] = *(const f16x8*)&as[cur][(wm + mt * 16 + l15) * 64 + (((kc * 4 + quad) ^ (l15 & 7)) * 8)];
#pragma unroll
    for (int kc = 0; kc < 2; ++kc)
#pragma unroll
      for (int nt = 0; nt < 4; ++nt) {
        const f16x8 bf = *(const f16x8*)&bs[cur][(wn + nt * 16 + l15) * 64 + (((kc * 4 + quad) ^ (l15 & 7)) * 8)];
#pragma unroll
        for (int mt = 0; mt < 4; ++mt)
          acc[mt][nt] = __builtin_amdgcn_mfma_f32_16x16x32_f16(af[mt][kc], bf, acc[mt][nt], 0, 0, 0);
      }
    __syncthreads();
    cur ^= 1;
  }

#pragma unroll
  for (int nt = 0; nt < 4; ++nt) {
    const int col = n0 + wn + nt * 16 + l15;
    const float bdv = bd[col];
#pragma unroll
    for (int mt = 0; mt < 4; ++mt)
#pragma unroll
      for (int r = 0; r < 4; ++r)
        out[(size_t)(m0 + wm + mt * 16 + quad * 4 + r) * E + col] = acc[mt][nt][r] + bdv;
  }
}

extern "C" void kernel_launch(void* const* d_in, const int* in_sizes, int n_in,
                              void* d_out, int out_size, void* d_ws, size_t ws_size,
                              hipStream_t stream) {
  const float* queries = (const float*)d_in[0];
  const float* values  = (const float*)d_in[1];
  const float* Wv = (const float*)d_in[3];
  const float* bv = (const float*)d_in[4];
  const float* Wk = (const float*)d_in[5];
  const float* bk = (const float*)d_in[6];
  const float* Wq = (const float*)d_in[7];
  const float* bq = (const float*)d_in[8];
  const float* Wd = (const float*)d_in[9];
  const float* bd = (const float*)d_in[10];
  float* out = (float*)d_out;

  char* ws = (char*)d_ws;
  f16* qp    = (f16*)(ws);                          // 8 MB [B,H,S,D]
  f16* kp    = (f16*)(ws + 8u * 1024 * 1024);       // 8 MB
  f16* vp    = (f16*)(ws + 16u * 1024 * 1024);      // 8 MB
  f16* ao    = (f16*)(ws + 24u * 1024 * 1024);      // 8 MB [B,S,E]
  f16* wd16  = (f16*)(ws + 32u * 1024 * 1024);      // 2 MB
  float* wkv = (float*)(ws + 34u * 1024 * 1024);    // 16 KB
  float* bkv = (float*)(ws + 34u * 1024 * 1024 + 16384);
  (void)ws_size; (void)in_sizes; (void)n_in; (void)out_size;

  prep<<<1040, 256, 0, stream>>>(Wd, wd16, Wk, Wv, bv, bk, wkv, bkv);
  proj3_mfma<<<dim3(256, 2), 256, 0, stream>>>(queries, values, Wq, bq, Wv, bv, wkv, bkv, qp, vp, kp);
  attn_mfma<<<dim3(B * H, S / 128), 256, 0, stream>>>(qp, kp, vp, ao);
  dense_mfma<<<dim3(B * S / 128, E / 128), 256, 0, stream>>>(ao, wd16, bd, out);
}